// Round 23
// baseline (102.321 us; speedup 1.0000x reference)
//
#include <hip/hip_runtime.h>
#include <math.h>

#define B_    16
#define CIN   64
#define COUT  128
#define H_    128
#define W_    128
#define CI2   128            // 2*CIN (x ++ silu(x))
#define KTOT  1152           // 9 taps * CI2

typedef __bf16 bf16x8 __attribute__((ext_vector_type(8)));
typedef float  f32x4  __attribute__((ext_vector_type(4)));

#define XT_BYTES  ((size_t)B_ * H_ * W_ * CI2 * 2)   // 67,108,864
#define WC_BYTES  ((size_t)COUT * KTOT * 2)          // 294,912
#define Z_OFF     (XT_BYTES + WC_BYTES)
#define WS_NEED   (Z_OFF + 4096)

// ---------- prep 1: weights -> Wc, QUARTER-TAP fragment order (r17-verified) ----
// quarter qq = (ks>>1)*18 + tap*2 + (ks&1) in [0,36); frag f = co>>4 in [0,8)
// elem off = (qq*8 + f)*512 + (lq*16+l15)*8 + e  -> 8KB contiguous per quarter.
__global__ __launch_bounds__(256) void w_prep(const float* __restrict__ sw,
                                              const float* __restrict__ bw,
                                              __bf16* __restrict__ wc,
                                              float* __restrict__ zp) {
    const int i = blockIdx.x * 256 + threadIdx.x;
    if (blockIdx.x == 0) zp[threadIdx.x] = 0.f;  // zeros page (1 KiB)
    if (i >= COUT * KTOT) return;
    const int co = i / KTOT, k = i - co * KTOT;
    const int tap = k >> 7, ci2 = k & 127;
    float v;
    if (ci2 < CIN) {
        const float* p = sw + ((size_t)(co * CIN + ci2) * 9 + tap) * 4;
        v = p[0] + p[1] + p[2] + p[3];
    } else {
        v = bw[(size_t)(co * CIN + (ci2 - CIN)) * 9 + tap];
    }
    const int f = co >> 4, l15 = co & 15;
    const int ks = ci2 >> 5, lq = (ci2 >> 3) & 3, e = ci2 & 7;
    const int qq = (ks >> 1) * 18 + tap * 2 + (ks & 1);
    const size_t off = ((size_t)(qq * 8 + f)) * 512 + (lq * 16 + l15) * 8 + e;
    wc[off] = (__bf16)v;
}

// ---------- prep 2: x (NCHW fp32) -> Xt (NHWC bf16, ci2 = x ++ silu(x)) ----------
__global__ __launch_bounds__(256) void xt_prep(const float* __restrict__ x,
                                               __bf16* __restrict__ xt) {
    __shared__ __align__(16) __bf16 tile[64][136];
    const int t  = threadIdx.x;
    const int w0 = blockIdx.x * 64;
    const int h  = blockIdx.y;
    const int b  = blockIdx.z;
    const float* xb = x + ((size_t)(b * CIN) * H_ + h) * W_ + w0;
#pragma unroll
    for (int rep = 0; rep < 16; ++rep) {
        const int idx = rep * 256 + t;
        const int ci = idx >> 6, w = idx & 63;
        const float v = xb[(size_t)ci * H_ * W_ + w];
        tile[w][ci]       = (__bf16)v;
        tile[w][CIN + ci] = (__bf16)(v / (1.f + __expf(-v)));
    }
    __syncthreads();
    __bf16* ob = xt + (((size_t)b * H_ + h) * W_ + w0) * CI2;
#pragma unroll
    for (int rep = 0; rep < 4; ++rep) {
        const int idx = rep * 256 + t;
        const int w = idx >> 4, sl = idx & 15;
        *(bf16x8*)(ob + (size_t)w * CI2 + sl * 8) = *(const bf16x8*)(&tile[w][sl * 8]);
    }
}

// ---------- main: wide-tile K-split MFMA conv + B-register prefetch ----------
// block: 128 couts x (8h x 32w = 256 pos); 4 waves, each 128co x 64pos.
// LDS: B half-halo 10x34 cells x 128B = 43520B + A quarter dbuf 2x8192B = 59904B.
// 36 phases: {stage A(q+1) ; 8 af reads ; 32 MFMA (B from regs) ; prefetch B(q+1)}.
__global__ __launch_bounds__(256, 2) void kan_mfma(const __bf16* __restrict__ xt,
                                                   const __bf16* __restrict__ wc,
                                                   const float* __restrict__ zp,
                                                   float* __restrict__ out) {
    __shared__ __align__(16) char bh[2720 * 16];    // 340 cells * 128B
    __shared__ __align__(16) char asA[512 * 16];    // A quarter buf A: 8 KB
    __shared__ __align__(16) char asB[512 * 16];    // A quarter buf B: 8 KB
    const int t    = threadIdx.x;
    const int lane = t & 63, wn = t >> 6;           // 4 waves = 4 n-quadrants
    const int l15 = lane & 15, lq = lane >> 4;

    // XCD-chunked bijective swizzle (1024 % 8 == 0)
    const int orig = blockIdx.x;
    const int wid  = (orig & 7) * 128 + (orig >> 3);
    const int b  = wid >> 6;
    const int hy = (wid >> 2) & 15, wx = wid & 3;
    const int w0 = wx * 32, h0 = hy * 8;

    const size_t xbase = (size_t)b * (H_ * W_ * CI2);

    // ---- stage B ci2-half kk: 2720 16B slots; chunk swizzle q^(cell&7)
#define STAGEB_(kk)                                                             \
    _Pragma("unroll")                                                           \
    for (int i = 0; i < 11; ++i) {                                              \
        const int s = i * 256 + t;                                              \
        if (s < 2720) {                                                         \
            const int cell = s >> 3, q = s & 7;                                 \
            const int ih = cell / 34, iw = cell - ih * 34;                      \
            const int gh = h0 + ih - 1, gw = w0 + iw - 1;                       \
            const int chunk = q ^ (cell & 7);                                   \
            const void* src;                                                    \
            if (gh >= 0 && gh < H_ && gw >= 0 && gw < W_)                       \
                src = (const void*)(xt + xbase +                                \
                      ((size_t)(gh * W_ + gw)) * CI2 + (kk) * 64 + chunk * 8);  \
            else                                                                \
                src = (const void*)zp;                                          \
            __builtin_amdgcn_global_load_lds(                                   \
                (const __attribute__((address_space(1))) unsigned int*)src,     \
                (__attribute__((address_space(3))) unsigned int*)(bh + s * 16), \
                16, 0, 0);                                                      \
        }                                                                       \
    }

    // ---- stage one 8KB A quarter (512 x 16B, linear both sides)
#define STAGEQ_(buf, qq)                                                        \
    _Pragma("unroll")                                                           \
    for (int i = 0; i < 2; ++i) {                                               \
        const int s = i * 256 + t;                                              \
        __builtin_amdgcn_global_load_lds(                                       \
            (const __attribute__((address_space(1))) unsigned int*)              \
                (wc + (size_t)(qq) * 4096 + s * 8),                             \
            (__attribute__((address_space(3))) unsigned int*)((buf) + s * 16),  \
            16, 0, 0);                                                          \
    }

    // ---- prefetch 4 B fragments for (tap tp, k-slice ksl) into regs
#define LOADB_(dst, tp, ksl)                                                    \
    {                                                                           \
        const int kh_ = ((tp) * 11) >> 5;                                       \
        const int kw_ = (tp) - kh_ * 3;                                         \
        _Pragma("unroll")                                                       \
        for (int n = 0; n < 4; ++n) {                                           \
            const int cell = (wn * 2 + (n >> 1) + kh_) * 34 +                   \
                             (n & 1) * 16 + l15 + kw_;                          \
            const int swz  = ((ksl) * 4 + lq) ^ (cell & 7);                     \
            dst[n] = *(const bf16x8*)(bh + cell * 128 + swz * 16);              \
        }                                                                       \
    }

    // ---- one phase: 8 af LDS reads + 32 MFMA, B operands from regs
#define COMPUTE_(buf, bfr)                                                      \
    {                                                                           \
        bf16x8 af[8];                                                           \
        _Pragma("unroll")                                                       \
        for (int m = 0; m < 8; ++m)                                             \
            af[m] = *(const bf16x8*)((buf) + m * 1024 + lane * 16);             \
        __builtin_amdgcn_s_setprio(1);                                          \
        _Pragma("unroll")                                                       \
        for (int m = 0; m < 8; ++m)                                             \
            _Pragma("unroll")                                                   \
            for (int n = 0; n < 4; ++n)                                         \
                acc[m][n] = __builtin_amdgcn_mfma_f32_16x16x32_bf16(            \
                    af[m], bfr[n], acc[m][n], 0, 0, 0);                         \
        __builtin_amdgcn_s_setprio(0);                                          \
    }

    f32x4 acc[8][4] = {};
    bf16x8 bfP[4], bfQ[4];

    STAGEB_(0);
    STAGEQ_(asA, 0);
    __syncthreads();                 // B half 0 + A quarter 0 ready
    LOADB_(bfP, 0, 0);

#pragma unroll 1
    for (int kk = 0; kk < 2; ++kk) {
        if (kk) {
            STAGEB_(1);              // previous barrier freed bh
            __syncthreads();         // bh half 1 (+ pending A q18/q19) ready
            LOADB_(bfP, 0, 0);
        }
#pragma unroll 1
        for (int tap = 0; tap < 9; ++tap) {
            const int qq = kk * 18 + tap * 2;
            // phase ksl=0: A in asA (ready); stage qq+1 -> asB; prefetch bf(ksl=1)
            STAGEQ_(asB, qq + 1);
            COMPUTE_(asA, bfP);
            LOADB_(bfQ, tap, 1);
            __syncthreads();
            // phase ksl=1: A in asB; stage qq+2 -> asA; prefetch next tap's bf
            if (kk == 0 || tap < 8) STAGEQ_(asA, qq + 2);
            COMPUTE_(asB, bfQ);
            if (tap < 8) LOADB_(bfP, tap + 1, 0);   // same kk-half: bh stable
            __syncthreads();
        }
    }

    // ---- epilogue: co = m*16 + lq*4 + r; oh = h0+wn*2+(n>>1); ow = w0+(n&1)*16+l15
    float* ob = out + (size_t)b * COUT * H_ * W_;
#pragma unroll
    for (int m = 0; m < 8; ++m) {
        const int co = m * 16 + lq * 4;
#pragma unroll
        for (int n = 0; n < 4; ++n) {
            const int oh = h0 + wn * 2 + (n >> 1);
            const int ow = w0 + (n & 1) * 16 + l15;
            float* p = ob + ((size_t)co * H_ + oh) * W_ + ow;
#pragma unroll
            for (int r = 0; r < 4; ++r)
                p[(size_t)r * H_ * W_] = acc[m][n][r];
        }
    }
#undef STAGEB_
#undef STAGEQ_
#undef LOADB_
#undef COMPUTE_
}

// ---------- fallback (round-0 fp32 path, used only if ws too small) ----------
#define TS   16
#define COB  8
#define TIN  18
__global__ __launch_bounds__(256) void spline_sum_kernel(const float* __restrict__ sw,
                                                         float* __restrict__ wsum) {
    int i = blockIdx.x * 256 + threadIdx.x;
    if (i < COUT * CIN * 9) {
        const float4 v = *reinterpret_cast<const float4*>(sw + (size_t)i * 4);
        wsum[i] = v.x + v.y + v.z + v.w;
    }
}
__global__ __launch_bounds__(256) void kan_conv(const float* __restrict__ x,
                                                const float* __restrict__ wsp,
                                                const float* __restrict__ wb,
                                                float* __restrict__ out) {
    __shared__ float xsm[TIN][20];
    __shared__ float ssm[TIN][20];
    const int t = threadIdx.x, tx = t & 15, ty = t >> 4;
    const int w0 = (blockIdx.x & 7) * TS, h0 = (blockIdx.x >> 3) * TS;
    const int co0 = blockIdx.y * COB, b = blockIdx.z;
    float acc[COB];
#pragma unroll
    for (int i = 0; i < COB; ++i) acc[i] = 0.f;
    const float* xb = x + (size_t)b * CIN * H_ * W_;
    for (int ci = 0; ci < CIN; ++ci) {
        __syncthreads();
        const float* xc = xb + (size_t)ci * H_ * W_;
        for (int p = t; p < TIN * TIN; p += 256) {
            int r = p / TIN, c = p - r * TIN;
            int ih = h0 + r - 1, iw = w0 + c - 1;
            float v = 0.f;
            if (ih >= 0 && ih < H_ && iw >= 0 && iw < W_) v = xc[ih * W_ + iw];
            xsm[r][c] = v;
            ssm[r][c] = v / (1.f + expf(-v));
        }
        __syncthreads();
        float xv[9], sv[9];
#pragma unroll
        for (int kh = 0; kh < 3; ++kh)
#pragma unroll
            for (int kw = 0; kw < 3; ++kw) {
                xv[kh * 3 + kw] = xsm[ty + kh][tx + kw];
                sv[kh * 3 + kw] = ssm[ty + kh][tx + kw];
            }
#pragma unroll
        for (int co = 0; co < COB; ++co) {
            const float* w1 = wsp + ((size_t)(co0 + co) * CIN + ci) * 9;
            const float* w2 = wb  + ((size_t)(co0 + co) * CIN + ci) * 9;
#pragma unroll
            for (int k = 0; k < 9; ++k)
                acc[co] += xv[k] * w1[k] + sv[k] * w2[k];
        }
    }
    const int oh = h0 + ty, ow = w0 + tx;
#pragma unroll
    for (int co = 0; co < COB; ++co)
        out[(((size_t)b * COUT + (co0 + co)) * H_ + oh) * W_ + ow] = acc[co];
}

extern "C" void kernel_launch(void* const* d_in, const int* in_sizes, int n_in,
                              void* d_out, int out_size, void* d_ws, size_t ws_size,
                              hipStream_t stream) {
    const float* x  = (const float*)d_in[0];
    const float* sw = (const float*)d_in[1];   // (COUT,CIN,3,3,4)
    const float* bw = (const float*)d_in[2];   // (COUT,CIN,3,3)
    float* out = (float*)d_out;

    if (ws_size >= WS_NEED) {
        __bf16* xt = (__bf16*)d_ws;
        __bf16* wc = (__bf16*)((char*)d_ws + XT_BYTES);
        float*  zp = (float*)((char*)d_ws + Z_OFF);
        w_prep<<<(COUT * KTOT + 255) / 256, 256, 0, stream>>>(sw, bw, wc, zp);
        xt_prep<<<dim3(2, H_, B_), 256, 0, stream>>>(x, xt);
        kan_mfma<<<dim3(1024), 256, 0, stream>>>(xt, wc, zp, out);
    } else {
        float* wsum = (float*)d_ws;
        spline_sum_kernel<<<(COUT * CIN * 9 + 255) / 256, 256, 0, stream>>>(sw, wsum);
        kan_conv<<<dim3(64, COUT / COB, B_), 256, 0, stream>>>(x, wsum, bw, out);
    }
}

// Round 24
// 100.245 us; speedup vs baseline: 1.0207x; 1.0207x over previous
//
#include <hip/hip_runtime.h>
#include <math.h>

#define B_    16
#define CIN   64
#define COUT  128
#define H_    128
#define W_    128
#define CI2   128            // 2*CIN (x ++ silu(x))
#define KTOT  1152           // 9 taps * CI2

typedef __bf16 bf16x8 __attribute__((ext_vector_type(8)));
typedef float  f32x4  __attribute__((ext_vector_type(4)));

#define XT_BYTES  ((size_t)B_ * H_ * W_ * CI2 * 2)   // 67,108,864
#define WC_BYTES  ((size_t)COUT * KTOT * 2)          // 294,912
#define Z_OFF     (XT_BYTES + WC_BYTES)
#define WS_NEED   (Z_OFF + 4096)

// ---------- prep 1: weights -> Wc, CHUNK-major fragment order ----------
// chunk c = kk*9 + tap in [0,18)  (kk = ci2>>6 = K-half)
// within chunk: subfrag (f = co>>4 in [0,8), j = (ci2>>5)&1), lane = lq*16+l15
// elem off = ((c*16 + f*2 + j)*64 + lq*16 + l15)*8 + e  -> 16KB contiguous/chunk.
__global__ __launch_bounds__(256) void w_prep(const float* __restrict__ sw,
                                              const float* __restrict__ bw,
                                              __bf16* __restrict__ wc,
                                              float* __restrict__ zp) {
    const int i = blockIdx.x * 256 + threadIdx.x;
    if (blockIdx.x == 0) zp[threadIdx.x] = 0.f;  // zeros page (1 KiB)
    if (i >= COUT * KTOT) return;
    const int co = i / KTOT, k = i - co * KTOT;
    const int tap = k >> 7, ci2 = k & 127;
    float v;
    if (ci2 < CIN) {
        const float* p = sw + ((size_t)(co * CIN + ci2) * 9 + tap) * 4;
        v = p[0] + p[1] + p[2] + p[3];
    } else {
        v = bw[(size_t)(co * CIN + (ci2 - CIN)) * 9 + tap];
    }
    const int f = co >> 4, l15 = co & 15;
    const int kk = ci2 >> 6, j = (ci2 >> 5) & 1;
    const int lq = (ci2 >> 3) & 3, e = ci2 & 7;
    const int c = kk * 9 + tap;
    const size_t off = ((size_t)(c * 16 + f * 2 + j)) * 512 + (lq * 16 + l15) * 8 + e;
    wc[off] = (__bf16)v;
}

// ---------- prep 2: x (NCHW fp32) -> Xt (NHWC bf16, ci2 = x ++ silu(x)) ----------
__global__ __launch_bounds__(256) void xt_prep(const float* __restrict__ x,
                                               __bf16* __restrict__ xt) {
    __shared__ __align__(16) __bf16 tile[64][136];
    const int t  = threadIdx.x;
    const int w0 = blockIdx.x * 64;
    const int h  = blockIdx.y;
    const int b  = blockIdx.z;
    const float* xb = x + ((size_t)(b * CIN) * H_ + h) * W_ + w0;
#pragma unroll
    for (int rep = 0; rep < 16; ++rep) {
        const int idx = rep * 256 + t;
        const int ci = idx >> 6, w = idx & 63;
        const float v = xb[(size_t)ci * H_ * W_ + w];
        tile[w][ci]       = (__bf16)v;
        tile[w][CIN + ci] = (__bf16)(v / (1.f + __expf(-v)));
    }
    __syncthreads();
    __bf16* ob = xt + (((size_t)b * H_ + h) * W_ + w0) * CI2;
#pragma unroll
    for (int rep = 0; rep < 4; ++rep) {
        const int idx = rep * 256 + t;
        const int w = idx >> 4, sl = idx & 15;
        *(bf16x8*)(ob + (size_t)w * CI2 + sl * 8) = *(const bf16x8*)(&tile[w][sl * 8]);
    }
}

// ---------- main: wide-tile K-split MFMA conv, 18 phases of K=64 ----------
// block: 128 couts x (8h x 32w = 256 pos); 4 waves, each 128co x 64pos.
// LDS: B half-halo 10x34 cells x 128B = 43520B + A chunk dbuf 2x16384B = 76288B.
// phase c: {stage A(c+1) ; 2x(8 af + 4 bf reads, 32 MFMA) ; barrier}.
__global__ __launch_bounds__(256, 2) void kan_mfma(const __bf16* __restrict__ xt,
                                                   const __bf16* __restrict__ wc,
                                                   const float* __restrict__ zp,
                                                   float* __restrict__ out) {
    __shared__ __align__(16) char bh[2720 * 16];     // 340 cells * 128B
    __shared__ __align__(16) char asA[1024 * 16];    // A chunk buf A: 16 KB
    __shared__ __align__(16) char asB[1024 * 16];    // A chunk buf B: 16 KB
    const int t    = threadIdx.x;
    const int lane = t & 63, wn = t >> 6;            // 4 waves = 4 n-quadrants
    const int l15 = lane & 15, lq = lane >> 4;

    // XCD-chunked bijective swizzle (1024 % 8 == 0)
    const int orig = blockIdx.x;
    const int wid  = (orig & 7) * 128 + (orig >> 3);
    const int b  = wid >> 6;
    const int hy = (wid >> 2) & 15, wx = wid & 3;
    const int w0 = wx * 32, h0 = hy * 8;

    const size_t xbase = (size_t)b * (H_ * W_ * CI2);

    // ---- stage B ci2-half kk: 2720 16B slots; chunk swizzle q^(cell&7)
#define STAGEB_(kk)                                                             \
    _Pragma("unroll")                                                           \
    for (int i = 0; i < 11; ++i) {                                              \
        const int s = i * 256 + t;                                              \
        if (s < 2720) {                                                         \
            const int cell = s >> 3, q = s & 7;                                 \
            const int ih = cell / 34, iw = cell - ih * 34;                      \
            const int gh = h0 + ih - 1, gw = w0 + iw - 1;                       \
            const int chunk = q ^ (cell & 7);                                   \
            const void* src;                                                    \
            if (gh >= 0 && gh < H_ && gw >= 0 && gw < W_)                       \
                src = (const void*)(xt + xbase +                                \
                      ((size_t)(gh * W_ + gw)) * CI2 + (kk) * 64 + chunk * 8);  \
            else                                                                \
                src = (const void*)zp;                                          \
            __builtin_amdgcn_global_load_lds(                                   \
                (const __attribute__((address_space(1))) unsigned int*)src,     \
                (__attribute__((address_space(3))) unsigned int*)(bh + s * 16), \
                16, 0, 0);                                                      \
        }                                                                       \
    }

    // ---- stage one 16KB A chunk (1024 x 16B, linear both sides)
#define STAGEC_(buf, c)                                                         \
    _Pragma("unroll")                                                           \
    for (int i = 0; i < 4; ++i) {                                               \
        const int s = i * 256 + t;                                              \
        __builtin_amdgcn_global_load_lds(                                       \
            (const __attribute__((address_space(1))) unsigned int*)              \
                (wc + (size_t)(c) * 8192 + s * 8),                              \
            (__attribute__((address_space(3))) unsigned int*)((buf) + s * 16),  \
            16, 0, 0);                                                          \
    }

    // ---- one phase: 2 j-groups of {8 af + 4 bf reads, 32 MFMA}
#define COMPUTE_(buf, tp)                                                       \
    {                                                                           \
        const int kh_ = ((tp) * 11) >> 5;                                       \
        const int kw_ = (tp) - kh_ * 3;                                         \
        _Pragma("unroll")                                                       \
        for (int j = 0; j < 2; ++j) {                                           \
            bf16x8 af[8], bf[4];                                                \
            _Pragma("unroll")                                                   \
            for (int m = 0; m < 8; ++m)                                         \
                af[m] = *(const bf16x8*)((buf) + (m * 2 + j) * 1024 +           \
                                         lane * 16);                            \
            _Pragma("unroll")                                                   \
            for (int n = 0; n < 4; ++n) {                                       \
                const int cell = (wn * 2 + (n >> 1) + kh_) * 34 +               \
                                 (n & 1) * 16 + l15 + kw_;                      \
                const int swz  = (j * 4 + lq) ^ (cell & 7);                     \
                bf[n] = *(const bf16x8*)(bh + cell * 128 + swz * 16);           \
            }                                                                   \
            __builtin_amdgcn_s_setprio(1);                                      \
            _Pragma("unroll")                                                   \
            for (int m = 0; m < 8; ++m)                                         \
                _Pragma("unroll")                                               \
                for (int n = 0; n < 4; ++n)                                     \
                    acc[m][n] = __builtin_amdgcn_mfma_f32_16x16x32_bf16(        \
                        af[m], bf[n], acc[m][n], 0, 0, 0);                      \
            __builtin_amdgcn_s_setprio(0);                                      \
        }                                                                       \
    }

    f32x4 acc[8][4] = {};

    STAGEB_(0);
    STAGEC_(asA, 0);
    __syncthreads();                 // B half 0 + A chunk 0 ready

#pragma unroll 1
    for (int kk = 0; kk < 2; ++kk) {
        if (kk) {
            STAGEB_(1);              // previous barrier freed bh
            __syncthreads();         // bh half 1 (+ pending A chunk 9) ready
        }
#pragma unroll 1
        for (int tap = 0; tap < 9; ++tap) {
            const int c = kk * 9 + tap;
            if (c < 17) STAGEC_((c & 1) ? asA : asB, c + 1);
            COMPUTE_((c & 1) ? asB : asA, tap);
            __syncthreads();         // drains stage(c+1); frees cur buf
        }
    }

    // ---- epilogue: co = m*16 + lq*4 + r; oh = h0+wn*2+(n>>1); ow = w0+(n&1)*16+l15
    float* ob = out + (size_t)b * COUT * H_ * W_;
#pragma unroll
    for (int m = 0; m < 8; ++m) {
        const int co = m * 16 + lq * 4;
#pragma unroll
        for (int n = 0; n < 4; ++n) {
            const int oh = h0 + wn * 2 + (n >> 1);
            const int ow = w0 + (n & 1) * 16 + l15;
            float* p = ob + ((size_t)co * H_ + oh) * W_ + ow;
#pragma unroll
            for (int r = 0; r < 4; ++r)
                p[(size_t)r * H_ * W_] = acc[m][n][r];
        }
    }
#undef STAGEB_
#undef STAGEC_
#undef COMPUTE_
}

// ---------- fallback (round-0 fp32 path, used only if ws too small) ----------
#define TS   16
#define COB  8
#define TIN  18
__global__ __launch_bounds__(256) void spline_sum_kernel(const float* __restrict__ sw,
                                                         float* __restrict__ wsum) {
    int i = blockIdx.x * 256 + threadIdx.x;
    if (i < COUT * CIN * 9) {
        const float4 v = *reinterpret_cast<const float4*>(sw + (size_t)i * 4);
        wsum[i] = v.x + v.y + v.z + v.w;
    }
}
__global__ __launch_bounds__(256) void kan_conv(const float* __restrict__ x,
                                                const float* __restrict__ wsp,
                                                const float* __restrict__ wb,
                                                float* __restrict__ out) {
    __shared__ float xsm[TIN][20];
    __shared__ float ssm[TIN][20];
    const int t = threadIdx.x, tx = t & 15, ty = t >> 4;
    const int w0 = (blockIdx.x & 7) * TS, h0 = (blockIdx.x >> 3) * TS;
    const int co0 = blockIdx.y * COB, b = blockIdx.z;
    float acc[COB];
#pragma unroll
    for (int i = 0; i < COB; ++i) acc[i] = 0.f;
    const float* xb = x + (size_t)b * CIN * H_ * W_;
    for (int ci = 0; ci < CIN; ++ci) {
        __syncthreads();
        const float* xc = xb + (size_t)ci * H_ * W_;
        for (int p = t; p < TIN * TIN; p += 256) {
            int r = p / TIN, c = p - r * TIN;
            int ih = h0 + r - 1, iw = w0 + c - 1;
            float v = 0.f;
            if (ih >= 0 && ih < H_ && iw >= 0 && iw < W_) v = xc[ih * W_ + iw];
            xsm[r][c] = v;
            ssm[r][c] = v / (1.f + expf(-v));
        }
        __syncthreads();
        float xv[9], sv[9];
#pragma unroll
        for (int kh = 0; kh < 3; ++kh)
#pragma unroll
            for (int kw = 0; kw < 3; ++kw) {
                xv[kh * 3 + kw] = xsm[ty + kh][tx + kw];
                sv[kh * 3 + kw] = ssm[ty + kh][tx + kw];
            }
#pragma unroll
        for (int co = 0; co < COB; ++co) {
            const float* w1 = wsp + ((size_t)(co0 + co) * CIN + ci) * 9;
            const float* w2 = wb  + ((size_t)(co0 + co) * CIN + ci) * 9;
#pragma unroll
            for (int k = 0; k < 9; ++k)
                acc[co] += xv[k] * w1[k] + sv[k] * w2[k];
        }
    }
    const int oh = h0 + ty, ow = w0 + tx;
#pragma unroll
    for (int co = 0; co < COB; ++co)
        out[(((size_t)b * COUT + (co0 + co)) * H_ + oh) * W_ + ow] = acc[co];
}

extern "C" void kernel_launch(void* const* d_in, const int* in_sizes, int n_in,
                              void* d_out, int out_size, void* d_ws, size_t ws_size,
                              hipStream_t stream) {
    const float* x  = (const float*)d_in[0];
    const float* sw = (const float*)d_in[1];   // (COUT,CIN,3,3,4)
    const float* bw = (const float*)d_in[2];   // (COUT,CIN,3,3)
    float* out = (float*)d_out;

    if (ws_size >= WS_NEED) {
        __bf16* xt = (__bf16*)d_ws;
        __bf16* wc = (__bf16*)((char*)d_ws + XT_BYTES);
        float*  zp = (float*)((char*)d_ws + Z_OFF);
        w_prep<<<(COUT * KTOT + 255) / 256, 256, 0, stream>>>(sw, bw, wc, zp);
        xt_prep<<<dim3(2, H_, B_), 256, 0, stream>>>(x, xt);
        kan_mfma<<<dim3(1024), 256, 0, stream>>>(xt, wc, zp, out);
    } else {
        float* wsum = (float*)d_ws;
        spline_sum_kernel<<<(COUT * CIN * 9 + 255) / 256, 256, 0, stream>>>(sw, wsum);
        kan_conv<<<dim3(64, COUT / COB, B_), 256, 0, stream>>>(x, wsum, bw, out);
    }
}